// Round 15
// baseline (694.690 us; speedup 1.0000x reference)
//
#include <hip/hip_runtime.h>
#include <math.h>

#define N_NODES 207
#define T_STEPS 12
#define NT 2484
#define BQ 4
#define DIM 96
#define NH 4
#define HD 24
#define FFD 384
#define N_MASK 1863
#define N_UNMASK 621
#define MAX_NEIGH 40
#define ATTN_SCALE 0.20412414523193154f   /* 1/sqrt(24) */
#define SQRT_DF 9.797958971132712f        /* sqrt(96) */
#define KT 256
#define NMW 20                            /* mask words per q (621 bits) */
#define NBH 16                            /* BQ*NH */

static inline int cdiv(int a, int b) { return (a + b - 1) / b; }

// ---------------------------------------------------------------------------
// Adjacency: A = softmax(relu(nv1@nv2), axis=1); keep = (A>1/207)&(A>kth41)
// ---------------------------------------------------------------------------
__global__ __launch_bounds__(256) void adj_kernel(const float* __restrict__ nv1,
                                                  const float* __restrict__ nv2,
                                                  float* __restrict__ keep) {
    int r = blockIdx.x, t = threadIdx.x;
    __shared__ float a[N_NODES];
    __shared__ float red[256];
    __shared__ int   redi[256];
    __shared__ int   taken[N_NODES];
    __shared__ float v1[10];
    __shared__ float kth;
    if (t < 10) v1[t] = nv1[r * 10 + t];
    __syncthreads();
    if (t < N_NODES) {
        float s = 0.f;
#pragma unroll
        for (int c = 0; c < 10; ++c) s += v1[c] * nv2[c * N_NODES + t];
        a[t] = fmaxf(s, 0.f);
        taken[t] = 0;
    }
    __syncthreads();
    red[t] = (t < N_NODES) ? a[t] : -3e38f;
    __syncthreads();
    for (int s = 128; s > 0; s >>= 1) {
        if (t < s) red[t] = fmaxf(red[t], red[t + s]);
        __syncthreads();
    }
    float mx = red[0];
    __syncthreads();
    float e = 0.f;
    if (t < N_NODES) e = __expf(a[t] - mx);
    red[t] = e;
    __syncthreads();
    for (int s = 128; s > 0; s >>= 1) {
        if (t < s) red[t] += red[t + s];
        __syncthreads();
    }
    float inv = 1.f / red[0];
    __syncthreads();
    if (t < N_NODES) a[t] = e * inv;
    __syncthreads();
    for (int round = 0; round <= MAX_NEIGH; ++round) {
        red[t]  = (t < N_NODES && !taken[t]) ? a[t] : -1.f;
        redi[t] = t;
        __syncthreads();
        for (int s = 128; s > 0; s >>= 1) {
            if (t < s && red[t + s] > red[t]) { red[t] = red[t + s]; redi[t] = redi[t + s]; }
            __syncthreads();
        }
        if (t == 0) {
            taken[redi[0]] = 1;
            if (round == MAX_NEIGH) kth = red[0];
        }
        __syncthreads();
    }
    if (t < N_NODES) {
        float av = a[t];
        keep[r * N_NODES + t] = (av > (1.f / 207.f) && av > kth) ? 1.f : 0.f;
    }
}

// mask bitwords: bit k of mw[q][w] = keep[uidx[q]/12][uidx[k]/12]
__global__ void maskbits_kernel(const float* __restrict__ keep, const int* __restrict__ uidx,
                                unsigned int* __restrict__ mw) {
    int q = blockIdx.x;
    int w = threadIdx.x;
    if (w >= NMW) return;
    const float* krow = keep + (uidx[q] / T_STEPS) * N_NODES;
    unsigned int word = 0;
    for (int j = 0; j < 32; ++j) {
        int k = w * 32 + j;
        if (k < N_UNMASK && krow[uidx[k] / T_STEPS] != 0.f) word |= (1u << j);
    }
    mw[q * NMW + w] = word;
}

__global__ void encin_kernel(const float* __restrict__ hist, const int* __restrict__ uidx,
                             const float* __restrict__ dim_w, const float* __restrict__ dim_b,
                             const float* __restrict__ pos,
                             const float* __restrict__ tod_w, const float* __restrict__ tod_b,
                             const float* __restrict__ dow_w, const float* __restrict__ dow_b,
                             float* __restrict__ h) {
    int idx = blockIdx.x * blockDim.x + threadIdx.x;
    if (idx >= BQ * N_UNMASK * DIM) return;
    int d = idx % DIM;
    int q = (idx / DIM) % N_UNMASK;
    int b = idx / (DIM * N_UNMASK);
    int u = uidx[q];
    int n = u / T_STEPS, t = u % T_STEPS;
    const float* hp = hist + ((size_t)(b * T_STEPS + t) * N_NODES + n) * 4;
    float h0 = hp[0], dw = hp[2], td = hp[3];
    float val = h0 * dim_w[d] + dim_b[d] + pos[u * DIM + d]
              + td * tod_w[d] + tod_b[d] + dw * dow_w[d] + dow_b[d];
    h[idx] = val * SQRT_DF;
}

__global__ void hmasked_kernel(const float* __restrict__ hist, const int* __restrict__ midx,
                               const float* __restrict__ mask_token, const float* __restrict__ pos,
                               const float* __restrict__ tod_w, const float* __restrict__ tod_b,
                               const float* __restrict__ dow_w, const float* __restrict__ dow_b,
                               float* __restrict__ full) {
    int idx = blockIdx.x * blockDim.x + threadIdx.x;
    if (idx >= BQ * N_MASK * DIM) return;
    int d = idx % DIM;
    int j = (idx / DIM) % N_MASK;
    int b = idx / (DIM * N_MASK);
    int m = midx[j];
    int n = m / T_STEPS, t = m % T_STEPS;
    const float* hp = hist + ((size_t)(b * T_STEPS + t) * N_NODES + n) * 4;
    float dw = hp[2], td = hp[3];
    float val = mask_token[d] + pos[m * DIM + d]
              + td * tod_w[d] + tod_b[d] + dw * dow_w[d] + dow_b[d];
    full[((size_t)(b * NT) + N_UNMASK + j) * DIM + d] = val * SQRT_DF;
}

__global__ void label_kernel(const float* __restrict__ hist, const int* __restrict__ midx,
                             float* __restrict__ out) {
    int idx = blockIdx.x * blockDim.x + threadIdx.x;
    if (idx >= BQ * N_MASK) return;
    int j = idx % N_MASK;
    int b = idx / N_MASK;
    int m = midx[j];
    int n = m / T_STEPS, t = m % T_STEPS;
    out[BQ * N_MASK + idx] = hist[((size_t)(b * T_STEPS + t) * N_NODES + n) * 4 + 0];
}

// ---------------------------------------------------------------------------
// Tiled GEMM: 64x64 tile, LDS-staged A and W, 16x16 threads x (4x4) outputs.
// WMODE 0: W is [K][N] row-major.  WMODE 1: W is [3][96][96] concat (QKV).
// rmode 1: residual rows gathered from full-layout masked region.
// omode 1: C rows scattered to full layout (row b*NT + q, q in [0,621)).
// LNA 1: LayerNorm staged A rows (K==96), params g1/b1; if wb && bn==0 write
//        normalized rows back to wb. LNA 2: two chained LNs.
// CMB 1: A rows are reconstructed in-LDS from attention partials
//        (Pm/Pl/Pacc, Sq2, NS2) — fused attn_combine. K must be 96.
// ---------------------------------------------------------------------------
#define ACCROW(accv, av)                                          \
    accv.x += av.x*w0.x + av.y*w1.x + av.z*w2.x + av.w*w3.x;      \
    accv.y += av.x*w0.y + av.y*w1.y + av.z*w2.y + av.w*w3.y;      \
    accv.z += av.x*w0.z + av.y*w1.z + av.z*w2.z + av.w*w3.z;      \
    accv.w += av.x*w0.w + av.y*w1.w + av.z*w2.w + av.w*w3.w;

template<int WMODE, int LNA, int CMB>
__global__ __launch_bounds__(256) void tgemm_kernel(const float* __restrict__ A,
                                                    const float* __restrict__ W,
                                                    const float* __restrict__ bias,
                                                    const float* __restrict__ res,
                                                    float* __restrict__ C,
                                                    int M, int N, int K, int gm,
                                                    int relu, float scale, int rmode,
                                                    int omode,
                                                    const float* __restrict__ g1,
                                                    const float* __restrict__ b1,
                                                    const float* __restrict__ g2,
                                                    const float* __restrict__ b2,
                                                    float* __restrict__ wb,
                                                    const float* __restrict__ Pm2,
                                                    const float* __restrict__ Pl2,
                                                    const float* __restrict__ Pacc2,
                                                    int Sq2, int NS2) {
    __shared__ float As[64][100];
    __shared__ float Ws[96][64];
    __shared__ float lred[64][4];
    __shared__ float lmv[64][2];
    int tid = threadIdx.x;
    int bm = blockIdx.x % gm;
    int bn = blockIdx.x / gm;
    int m0 = bm * 64, n0 = bn * 64;
    int tn4 = (tid & 15) * 4;
    int tm4 = (tid >> 4) * 4;
    float4 acc0 = {0,0,0,0}, acc1 = {0,0,0,0}, acc2 = {0,0,0,0}, acc3 = {0,0,0,0};

    for (int kc = 0; kc < K; kc += 96) {
        if (kc) __syncthreads();
        if (CMB) {
            // fused attention combine: 4 threads per row, one head each
            int r = tid >> 2, hh2 = tid & 3;
            int grow = m0 + r;
            float o[24];
#pragma unroll
            for (int d = 0; d < 24; ++d) o[d] = 0.f;
            float Lv = 1.f;
            if (grow < M) {
                int bb = grow / Sq2, q = grow - bb * Sq2;
                int bh = bb * NH + hh2;
                float Mx = -1e30f;
                for (int ns = 0; ns < NS2; ++ns)
                    Mx = fmaxf(Mx, Pm2[((size_t)(ns * NBH + bh)) * Sq2 + q]);
                Lv = 0.f;
                for (int ns = 0; ns < NS2; ++ns) {
                    size_t pq = ((size_t)(ns * NBH + bh)) * Sq2 + q;
                    float wgt = __expf(Pm2[pq] - Mx);
                    Lv += wgt * Pl2[pq];
                    const float* pa = Pacc2 + pq * 24;
#pragma unroll
                    for (int i = 0; i < 6; ++i) {
                        float4 f = *(const float4*)(pa + i * 4);
                        o[i*4+0] += wgt * f.x; o[i*4+1] += wgt * f.y;
                        o[i*4+2] += wgt * f.z; o[i*4+3] += wgt * f.w;
                    }
                }
            }
            float inv = 1.f / Lv;
#pragma unroll
            for (int i = 0; i < 6; ++i)
                *(float4*)&As[r][hh2 * 24 + i * 4] =
                    make_float4(o[i*4+0] * inv, o[i*4+1] * inv,
                                o[i*4+2] * inv, o[i*4+3] * inv);
        } else {
#pragma unroll
            for (int i = 0; i < 6; ++i) {
                int f = i * 256 + tid;
                int r = f / 24, c4 = (f % 24) * 4;
                float4 v = {0,0,0,0};
                if (m0 + r < M) v = *(const float4*)(A + (size_t)(m0 + r) * K + kc + c4);
                *(float4*)&As[r][c4] = v;
            }
        }
#pragma unroll
        for (int i = 0; i < 6; ++i) {
            int f = i * 256 + tid;
            int kr = f >> 4, n4 = (f & 15) * 4;
            int gn = n0 + n4;
            float4 v = {0,0,0,0};
            if (gn < N) {
                if (WMODE == 0) {
                    v = *(const float4*)(W + (size_t)(kc + kr) * N + gn);
                } else {
                    int gg = gn / 96, nc = gn - gg * 96;
                    v = *(const float4*)(W + (size_t)gg * 9216 + (kc + kr) * 96 + nc);
                }
            }
            *(float4*)&Ws[kr][n4] = v;
        }
        __syncthreads();

        if (LNA > 0 && kc == 0) {        // LNA implies K == 96 (single chunk)
#pragma unroll
            for (int pass = 0; pass < LNA; ++pass) {
                const float* lg = pass ? g2 : g1;
                const float* lb = pass ? b2 : b1;
                int row = tid >> 2, part = tid & 3;
                float s = 0.f;
                for (int c = part * 24; c < part * 24 + 24; ++c) s += As[row][c];
                lred[row][part] = s;
                __syncthreads();
                float mean = (lred[row][0] + lred[row][1] + lred[row][2] + lred[row][3]) * (1.f / 96.f);
                float s2 = 0.f;
                for (int c = part * 24; c < part * 24 + 24; ++c) {
                    float d = As[row][c] - mean; s2 += d * d;
                }
                __syncthreads();
                lred[row][part] = s2;
                __syncthreads();
                if (part == 0) {
                    float var = (lred[row][0] + lred[row][1] + lred[row][2] + lred[row][3]) * (1.f / 96.f);
                    lmv[row][0] = mean;
                    lmv[row][1] = rsqrtf(var + 1e-5f);
                }
                __syncthreads();
#pragma unroll
                for (int i = 0; i < 6; ++i) {
                    int f = i * 256 + tid;
                    int r = f / 24, c4 = (f % 24) * 4;
                    float mn = lmv[r][0], rsd = lmv[r][1];
                    float4 v = *(float4*)&As[r][c4];
                    v.x = (v.x - mn) * rsd * lg[c4 + 0] + lb[c4 + 0];
                    v.y = (v.y - mn) * rsd * lg[c4 + 1] + lb[c4 + 1];
                    v.z = (v.z - mn) * rsd * lg[c4 + 2] + lb[c4 + 2];
                    v.w = (v.w - mn) * rsd * lg[c4 + 3] + lb[c4 + 3];
                    *(float4*)&As[r][c4] = v;
                }
                __syncthreads();
            }
            if (wb && bn == 0) {
#pragma unroll
                for (int i = 0; i < 6; ++i) {
                    int f = i * 256 + tid;
                    int r = f / 24, c4 = (f % 24) * 4;
                    if (m0 + r < M)
                        *(float4*)(wb + (size_t)(m0 + r) * 96 + c4) = *(const float4*)&As[r][c4];
                }
            }
        }

#pragma unroll 4
        for (int k = 0; k < 96; k += 4) {
            float4 a0 = *(const float4*)&As[tm4 + 0][k];
            float4 a1 = *(const float4*)&As[tm4 + 1][k];
            float4 a2 = *(const float4*)&As[tm4 + 2][k];
            float4 a3 = *(const float4*)&As[tm4 + 3][k];
            float4 w0 = *(const float4*)&Ws[k + 0][tn4];
            float4 w1 = *(const float4*)&Ws[k + 1][tn4];
            float4 w2 = *(const float4*)&Ws[k + 2][tn4];
            float4 w3 = *(const float4*)&Ws[k + 3][tn4];
            ACCROW(acc0, a0)
            ACCROW(acc1, a1)
            ACCROW(acc2, a2)
            ACCROW(acc3, a3)
        }
    }

    int gn = n0 + tn4;
    if (gn >= N) return;
    float4 bv = *(const float4*)(bias + gn);
    float4 av[4] = {acc0, acc1, acc2, acc3};
#pragma unroll
    for (int i = 0; i < 4; ++i) {
        int grow = m0 + tm4 + i;
        if (grow >= M) break;
        float4 acc = av[i];
        acc.x += bv.x; acc.y += bv.y; acc.z += bv.z; acc.w += bv.w;
        if (res) {
            int rr = grow;
            if (rmode) { int bb = grow / N_MASK; rr = bb * NT + N_UNMASK + (grow - bb * N_MASK); }
            float4 rv = *(const float4*)(res + (size_t)rr * N + gn);
            acc.x += rv.x; acc.y += rv.y; acc.z += rv.z; acc.w += rv.w;
        }
        if (relu) {
            acc.x = fmaxf(acc.x, 0.f); acc.y = fmaxf(acc.y, 0.f);
            acc.z = fmaxf(acc.z, 0.f); acc.w = fmaxf(acc.w, 0.f);
        }
        acc.x *= scale; acc.y *= scale; acc.z *= scale; acc.w *= scale;
        int orow = grow;
        if (omode) { int bb = grow / N_UNMASK; orow = bb * NT + (grow - bb * N_UNMASK); }
        *(float4*)(C + (size_t)orow * N + gn) = acc;
    }
}

// ---------------------------------------------------------------------------
// Flash attention stage 1 (K-split, fp32 partials, ns-major storage).
// K-tiles interleaved across ns (c = ns, ns+NS, ...). swz=1: XCD-chunked
// decode (grid == 8 * 2 * nqt*NS): xcd=bid&7 serves bh in {xcd, xcd+8}.
// ---------------------------------------------------------------------------
template<int QPL>
__global__ __launch_bounds__(256) void fattn_kernel(const float* __restrict__ Qp,
                                                    const float* __restrict__ Kp,
                                                    const float* __restrict__ Vp,
                                                    float* __restrict__ Pm,
                                                    float* __restrict__ Pl,
                                                    float* __restrict__ Pacc,
                                                    const unsigned int* __restrict__ maskw,
                                                    int swz,
                                                    int S, int Sq, int qoff,
                                                    int nqt, int NS, int rs) {
    __shared__ float smem[12288];
    float* Ks = smem;
    float* Vs = smem + 6144;

    int t = threadIdx.x;
    int w = t >> 6, lane = t & 63;
    int bid = blockIdx.x;
    int ns, qt, hh, b;
    if (swz) {
        int xcd = bid & 7, slot = bid >> 3;
        int spb = nqt * NS;
        int bh = xcd + 8 * (slot / spb);
        int r = slot % spb;
        qt = r / NS; ns = r % NS;
        b = bh >> 2; hh = bh & 3;
    } else {
        ns = bid % NS; int r1 = bid / NS;
        qt = r1 % nqt; r1 /= nqt;
        hh = r1 % NH; b = r1 / NH;
    }

    float qr[QPL][HD];
    bool qvalid[QPL];
#pragma unroll
    for (int h = 0; h < QPL; ++h) {
        int qidx = qt * (64 * QPL) + h * 64 + lane;
        qvalid[h] = qidx < Sq;
        if (qvalid[h]) {
            const float* qp = Qp + ((size_t)(b * S + qoff + qidx)) * rs + hh * HD;
#pragma unroll
            for (int i = 0; i < 6; ++i) {
                float4 v = *(const float4*)(qp + i * 4);
                qr[h][i*4+0] = v.x; qr[h][i*4+1] = v.y;
                qr[h][i*4+2] = v.z; qr[h][i*4+3] = v.w;
            }
        } else {
#pragma unroll
            for (int d = 0; d < HD; ++d) qr[h][d] = 0.f;
        }
    }

    float m[QPL], l[QPL];
    float acc[QPL][HD];
#pragma unroll
    for (int h = 0; h < QPL; ++h) {
        m[h] = -1e30f; l[h] = 0.f;
#pragma unroll
        for (int d = 0; d < HD; ++d) acc[h][d] = 0.f;
    }

    int ntile = (S + KT - 1) / KT;
    for (int c = ns; c < ntile; c += NS) {
        __syncthreads();
        int base_k = c * KT;
#pragma unroll
        for (int i = 0; i < 6; ++i) {
            int fi = i * 256 + t;
            int row = fi / 6, cc = fi - row * 6;
            int gk = base_k + row;
            float4 kv = {0,0,0,0};
            float4 vv = {0,0,0,0};
            if (gk < S) {
                size_t roff = ((size_t)(b * S + gk)) * rs + hh * HD + cc * 4;
                kv = *(const float4*)(Kp + roff);
                vv = *(const float4*)(Vp + roff);
            }
            *(float4*)(Ks + row * HD + cc * 4) = kv;
            *(float4*)(Vs + row * HD + cc * 4) = vv;
        }
        __syncthreads();

        unsigned int mw0 = ~0u, mw1 = ~0u;
        if (QPL == 1 && maskw) {
            int qidx = qt * 64 + lane;
            if (qidx < Sq) {
                int wi = c * 8 + w * 2;
                mw0 = (wi     < NMW) ? maskw[qidx * NMW + wi]     : 0u;
                mw1 = (wi + 1 < NMW) ? maskw[qidx * NMW + wi + 1] : 0u;
            }
        }

        for (int g = 0; g < 16; ++g) {
            float sgrp[QPL][4];
            float pv[QPL][4];
#pragma unroll
            for (int j = 0; j < 4; ++j) {
                int j2 = g * 4 + j;
                int kk = (w << 6) + j2;
                int gk = base_k + kk;
                const float4* kr = (const float4*)(Ks + kk * HD);
                float d0[QPL];
#pragma unroll
                for (int h = 0; h < QPL; ++h) d0[h] = 0.f;
#pragma unroll
                for (int i = 0; i < 6; ++i) {
                    float4 kv = kr[i];
#pragma unroll
                    for (int h = 0; h < QPL; ++h) {
                        d0[h] += qr[h][i*4+0]*kv.x + qr[h][i*4+1]*kv.y
                               + qr[h][i*4+2]*kv.z + qr[h][i*4+3]*kv.w;
                    }
                }
#pragma unroll
                for (int h = 0; h < QPL; ++h) {
                    float s = d0[h] * ATTN_SCALE;
                    if (QPL == 1 && maskw) {
                        unsigned int wsel = (j2 & 32) ? mw1 : mw0;
                        if (!((wsel >> (j2 & 31)) & 1u)) s = -1e30f;
                    }
                    if (gk >= S) s = -INFINITY;
                    sgrp[h][j] = s;
                }
            }
#pragma unroll
            for (int h = 0; h < QPL; ++h) {
                float gmx = fmaxf(fmaxf(sgrp[h][0], sgrp[h][1]),
                                  fmaxf(sgrp[h][2], sgrp[h][3]));
                if (gmx > m[h]) {
                    float f = __expf(m[h] - gmx);
                    l[h] *= f;
#pragma unroll
                    for (int d = 0; d < HD; ++d) acc[h][d] *= f;
                    m[h] = gmx;
                }
#pragma unroll
                for (int j = 0; j < 4; ++j) {
                    float p = __expf(sgrp[h][j] - m[h]);
                    pv[h][j] = p;
                    l[h] += p;
                }
            }
#pragma unroll
            for (int j = 0; j < 4; ++j) {
                int kk = (w << 6) + g * 4 + j;
                const float4* vr = (const float4*)(Vs + kk * HD);
#pragma unroll
                for (int i = 0; i < 6; ++i) {
                    float4 vv = vr[i];
#pragma unroll
                    for (int h = 0; h < QPL; ++h) {
                        acc[h][i*4+0] += pv[h][j]*vv.x;
                        acc[h][i*4+1] += pv[h][j]*vv.y;
                        acc[h][i*4+2] += pv[h][j]*vv.z;
                        acc[h][i*4+3] += pv[h][j]*vv.w;
                    }
                }
            }
        }
    }

#pragma unroll
    for (int h = 0; h < QPL; ++h) {
        __syncthreads();
        float* my = smem + (size_t)(w * 64 + lane) * 27;
        my[0] = m[h]; my[1] = l[h];
#pragma unroll
        for (int d = 0; d < HD; ++d) my[2 + d] = acc[h][d];
        __syncthreads();
        if (t < 64) {
            int qidx = qt * (64 * QPL) + h * 64 + t;
            if (qidx < Sq) {
                float M2 = -INFINITY;
#pragma unroll
                for (int w2 = 0; w2 < 4; ++w2)
                    M2 = fmaxf(M2, smem[(size_t)(w2 * 64 + t) * 27]);
                float L = 0.f;
                float o[HD];
#pragma unroll
                for (int d = 0; d < HD; ++d) o[d] = 0.f;
#pragma unroll
                for (int w2 = 0; w2 < 4; ++w2) {
                    const float* pp = smem + (size_t)(w2 * 64 + t) * 27;
                    float f = __expf(pp[0] - M2);
                    L += pp[1] * f;
#pragma unroll
                    for (int d = 0; d < HD; ++d) o[d] += pp[2 + d] * f;
                }
                int bh = b * NH + hh;
                size_t pq = ((size_t)(ns * NBH + bh)) * Sq + qidx;
                Pm[pq] = M2;
                Pl[pq] = L;
                float* pa = Pacc + pq * 24;
#pragma unroll
                for (int i = 0; i < 6; ++i)
                    *(float4*)(pa + i * 4) = make_float4(o[i*4+0], o[i*4+1],
                                                         o[i*4+2], o[i*4+3]);
            }
        }
    }
}

// fused LN -> LN -> out-projection for the masked tail rows
__global__ __launch_bounds__(256) void tail_kernel(const float* __restrict__ X,
                                                   const float* __restrict__ g1,
                                                   const float* __restrict__ b1,
                                                   const float* __restrict__ g2,
                                                   const float* __restrict__ b2,
                                                   const float* __restrict__ ow,
                                                   const float* __restrict__ ob,
                                                   float* __restrict__ out, int Mtail) {
    int row = blockIdx.x * 4 + (threadIdx.x >> 6);
    if (row >= Mtail) return;
    int lane = threadIdx.x & 63;
    bool lo = lane < 32;
    const float* x = X + (size_t)row * DIM;
    float x0 = x[lane];
    float x1 = lo ? x[64 + lane] : 0.f;
    float s = x0 + x1;
#pragma unroll
    for (int o = 32; o; o >>= 1) s += __shfl_xor(s, o);
    float mean = s * (1.f / DIM);
    float d0 = x0 - mean;
    float d1 = lo ? (x1 - mean) : 0.f;
    float v = d0 * d0 + d1 * d1;
#pragma unroll
    for (int o = 32; o; o >>= 1) v += __shfl_xor(v, o);
    float rs = rsqrtf(v * (1.f / DIM) + 1e-5f);
    float y0 = d0 * rs * g1[lane] + b1[lane];
    float y1 = lo ? (d1 * rs * g1[64 + lane] + b1[64 + lane]) : 0.f;
    s = y0 + y1;
#pragma unroll
    for (int o = 32; o; o >>= 1) s += __shfl_xor(s, o);
    mean = s * (1.f / DIM);
    d0 = y0 - mean;
    d1 = lo ? (y1 - mean) : 0.f;
    v = d0 * d0 + d1 * d1;
#pragma unroll
    for (int o = 32; o; o >>= 1) v += __shfl_xor(v, o);
    rs = rsqrtf(v * (1.f / DIM) + 1e-5f);
    float z0 = d0 * rs * g2[lane] + b2[lane];
    float z1 = lo ? (d1 * rs * g2[64 + lane] + b2[64 + lane]) : 0.f;
    float a = z0 * ow[lane] + (lo ? z1 * ow[64 + lane] : 0.f);
#pragma unroll
    for (int o = 32; o; o >>= 1) a += __shfl_xor(a, o);
    if (lane == 0) out[row] = a + ob[0];
}

extern "C" void kernel_launch(void* const* d_in, const int* in_sizes, int n_in,
                              void* d_out, int out_size, void* d_ws, size_t ws_size,
                              hipStream_t stream) {
    const float* hist   = (const float*)d_in[0];
    const int*   uidx   = (const int*)d_in[1];
    const int*   midx   = (const int*)d_in[2];
    const float* nv1    = (const float*)d_in[3];
    const float* nv2    = (const float*)d_in[4];
    const float* dim_w  = (const float*)d_in[5];
    const float* dim_b  = (const float*)d_in[6];
    const float* pos    = (const float*)d_in[7];
    const float* tod_w  = (const float*)d_in[8];
    const float* tod_b  = (const float*)d_in[9];
    const float* dow_w  = (const float*)d_in[10];
    const float* dow_b  = (const float*)d_in[11];
    const float* mtok   = (const float*)d_in[12];
    const float* eaw    = (const float*)d_in[13];
    const float* eab    = (const float*)d_in[14];
    const float* ew1    = (const float*)d_in[15];
    const float* eb1    = (const float*)d_in[16];
    const float* ew2    = (const float*)d_in[17];
    const float* eb2    = (const float*)d_in[18];
    const float* eln    = (const float*)d_in[19];
    const float* eng    = (const float*)d_in[20];
    const float* enb    = (const float*)d_in[21];
    const float* e2dw   = (const float*)d_in[22];
    const float* e2db   = (const float*)d_in[23];
    const float* daw    = (const float*)d_in[24];
    const float* dab    = (const float*)d_in[25];
    const float* dw1    = (const float*)d_in[26];
    const float* db1    = (const float*)d_in[27];
    const float* dw2    = (const float*)d_in[28];
    const float* db2    = (const float*)d_in[29];
    const float* dln    = (const float*)d_in[30];
    const float* dng    = (const float*)d_in[31];
    const float* dnb    = (const float*)d_in[32];
    const float* ow     = (const float*)d_in[33];
    const float* ob     = (const float*)d_in[34];

    float* ws = (float*)d_ws;
    float*        keep  = ws;                               // 0..43008
    unsigned int* maskw = (unsigned int*)(ws + 44032);      // ..56576
    float* eh = ws + 56576;            // [2484][96]  -> 295040
    float* e1 = ws + 295040;           // [2484][384] -> 1248896
    float* et = ws + 1487360;          // [2484][96]  -> 1725824
    float* fh = ws + 1725824;          // [9936][96]  -> 2679680
    float* qf = ws + 2679680;          // [9936][288] -> 5541248 (also dec FF-mid [7452][384])
    float* dh = ws + 5541248;          // [7452][96]  -> 6256640
    float* dt = ws + 6256640;          // [7452][96]  -> 6972032
    // encoder attn partials overlay dead dh (NSE=3, Sq=621):
    float* PaccE = ws + 5541248;       // 715392 -> 6256640
    float* PmE   = ws + 6256640;       // 29808 -> 6286448
    float* PlE   = ws + 6286448;       // 29808 -> 6316256
    // decoder attn partials overlay dead encoder temps (NSD=2, Sq=1863):
    float* PaccD = ws + 56576;         // 2*16*1863*24 = 1430784 -> 1487360
    float* PmD   = ws + 1487360;       // 59616 -> 1546976
    float* PlD   = ws + 1546976;       // 59616 -> 1606592 (< 1725824 = fh)
    // decoder post-attention temps:
    //   O-proj(CMB from partials, +fh res) -> dt ; FF1(LNA dt, wb=dZ) -> qf ;
    //   FF2(qf, +dZ res) -> dh ; tail(dh)
    float* dZ = ws + 771968;           // [7452][96] -> 1487360 (partials dead by FF1)

    float* outp = (float*)d_out;
    const int ME = BQ * N_UNMASK;   // 2484
    const int MD = BQ * NT;         // 9936
    const int MT = BQ * N_MASK;     // 7452
    const int gmE = cdiv(ME, 64);   // 39
    const int gmD = cdiv(MD, 64);   // 156
    const int gmT = cdiv(MT, 64);   // 117
    const int NSE = 3, NSD = 2;
    const int nqtE = 10;            // ceil(621/64),  QPL=1 ; grid 480 = 8*2*30
    const int nqtD = 30;            // ceil(1863/64), QPL=1 ; grid 960 = 8*2*60

    adj_kernel<<<N_NODES, 256, 0, stream>>>(nv1, nv2, keep);
    maskbits_kernel<<<N_UNMASK, 32, 0, stream>>>(keep, uidx, maskw);
    encin_kernel<<<cdiv(ME * DIM, 256), 256, 0, stream>>>(
        hist, uidx, dim_w, dim_b, pos, tod_w, tod_b, dow_w, dow_b, eh);
    label_kernel<<<cdiv(MT, 256), 256, 0, stream>>>(hist, midx, outp);

    // ---------------- encoder: 4 layers, S=621 ----------------
    for (int l = 0; l < 4; ++l) {
        const float* aw = eaw + (size_t)l * 4 * DIM * DIM;
        const float* ab = eab + (size_t)l * 4 * DIM;
        if (l == 0) {
            tgemm_kernel<1,0,0><<<gmE * 5, 256, 0, stream>>>(
                eh, aw, ab, nullptr, e1, ME, 288, 96, gmE, 0, 1.f, 0, 0,
                nullptr, nullptr, nullptr, nullptr, nullptr,
                nullptr, nullptr, nullptr, 0, 0);
        } else {
            // A = et (prev FF2 out, pre-LN2); LN2(l-1) fused; write back to eh
            tgemm_kernel<1,1,0><<<gmE * 5, 256, 0, stream>>>(
                et, aw, ab, nullptr, e1, ME, 288, 96, gmE, 0, 1.f, 0, 0,
                eln + (size_t)((l - 1) * 4 + 2) * DIM,
                eln + (size_t)((l - 1) * 4 + 3) * DIM,
                nullptr, nullptr, eh,
                nullptr, nullptr, nullptr, 0, 0);
        }
        fattn_kernel<1><<<NBH * nqtE * NSE, 256, 0, stream>>>(
            e1, e1 + 96, e1 + 192, PmE, PlE, PaccE, maskw, 1,
            N_UNMASK, N_UNMASK, 0, nqtE, NSE, 288);
        // O-proj with fused combine (A from partials) + residual eh -> et
        tgemm_kernel<0,0,1><<<gmE * 2, 256, 0, stream>>>(
            nullptr, aw + 3 * DIM * DIM, ab + 3 * DIM, eh, et, ME, 96, 96, gmE,
            0, 1.f, 0, 0,
            nullptr, nullptr, nullptr, nullptr, nullptr,
            PmE, PlE, PaccE, N_UNMASK, NSE);
        // FF1 with fused LN1 (A = et pre-LN1); write LN1 rows back to eh
        tgemm_kernel<0,1,0><<<gmE * 6, 256, 0, stream>>>(
            et, ew1 + (size_t)l * DIM * FFD, eb1 + (size_t)l * FFD, nullptr, e1,
            ME, FFD, 96, gmE, 1, 1.f, 0, 0,
            eln + (size_t)(l * 4 + 0) * DIM, eln + (size_t)(l * 4 + 1) * DIM,
            nullptr, nullptr, eh,
            nullptr, nullptr, nullptr, 0, 0);
        tgemm_kernel<0,0,0><<<gmE * 2, 256, 0, stream>>>(
            e1, ew2 + (size_t)l * FFD * DIM, eb2 + (size_t)l * DIM, eh, et,
            ME, 96, FFD, gmE, 0, 1.f, 0, 0,
            nullptr, nullptr, nullptr, nullptr, nullptr,
            nullptr, nullptr, nullptr, 0, 0);
        // (LN2 folded into next consumer's A-stage)
    }
    // e2d with fused LN2(l3) + final norm, *sqrt(D), scattered into fh (omode=1)
    tgemm_kernel<0,2,0><<<gmE * 2, 256, 0, stream>>>(
        et, e2dw, e2db, nullptr, fh, ME, 96, 96, gmE, 0, SQRT_DF, 0, 1,
        eln + (size_t)(3 * 4 + 2) * DIM, eln + (size_t)(3 * 4 + 3) * DIM,
        eng, enb, nullptr,
        nullptr, nullptr, nullptr, 0, 0);
    hmasked_kernel<<<cdiv(MT * DIM, 256), 256, 0, stream>>>(
        hist, midx, mtok, pos, tod_w, tod_b, dow_w, dow_b, fh);

    // ---------------- decoder: 1 layer; only masked q-rows survive ----------
    tgemm_kernel<1,0,0><<<gmD * 5, 256, 0, stream>>>(
        fh, daw, dab, nullptr, qf, MD, 288, 96, gmD, 0, 1.f, 0, 0,
        nullptr, nullptr, nullptr, nullptr, nullptr,
        nullptr, nullptr, nullptr, 0, 0);
    // QPL=1, NS=2, swizzled -> 960 blocks (q-axis occupancy instead of K-split)
    fattn_kernel<1><<<NBH * nqtD * NSD, 256, 0, stream>>>(
        qf, qf + 96, qf + 192, PmD, PlD, PaccD, nullptr, 1,
        NT, N_MASK, N_UNMASK, nqtD, NSD, 288);
    // O-proj with fused combine + residual gathered from fh (rmode=1) -> dt
    tgemm_kernel<0,0,1><<<gmT * 2, 256, 0, stream>>>(
        nullptr, daw + 3 * DIM * DIM, dab + 3 * DIM, fh, dt, MT, 96, 96, gmT,
        0, 1.f, 1, 0,
        nullptr, nullptr, nullptr, nullptr, nullptr,
        PmD, PlD, PaccD, N_MASK, NSD);
    // FF1 with fused LN1 (A = dt pre-LN1); write LN1 rows back to dZ
    tgemm_kernel<0,1,0><<<gmT * 6, 256, 0, stream>>>(
        dt, dw1, db1, nullptr, qf, MT, FFD, 96, gmT, 1, 1.f, 0, 0,
        dln + 0 * DIM, dln + 1 * DIM, nullptr, nullptr, dZ,
        nullptr, nullptr, nullptr, 0, 0);
    tgemm_kernel<0,0,0><<<gmT * 2, 256, 0, stream>>>(
        qf, dw2, db2, dZ, dh, MT, 96, FFD, gmT, 0, 1.f, 0, 0,
        nullptr, nullptr, nullptr, nullptr, nullptr,
        nullptr, nullptr, nullptr, 0, 0);
    tail_kernel<<<cdiv(MT, 4), 256, 0, stream>>>(
        dh, dln + 2 * DIM, dln + 3 * DIM, dng, dnb, ow, ob, outp, MT);
}

// Round 16
// 672.166 us; speedup vs baseline: 1.0335x; 1.0335x over previous
//
#include <hip/hip_runtime.h>
#include <math.h>

#define N_NODES 207
#define T_STEPS 12
#define NT 2484
#define BQ 4
#define DIM 96
#define NH 4
#define HD 24
#define FFD 384
#define N_MASK 1863
#define N_UNMASK 621
#define MAX_NEIGH 40
#define ATTN_SCALE 0.20412414523193154f   /* 1/sqrt(24) */
#define SQRT_DF 9.797958971132712f        /* sqrt(96) */
#define KT 256
#define NMW 20                            /* mask words per q (621 bits) */
#define NBH 16                            /* BQ*NH */

static inline int cdiv(int a, int b) { return (a + b - 1) / b; }

// ---------------------------------------------------------------------------
// Adjacency: A = softmax(relu(nv1@nv2), axis=1); keep = (A>1/207)&(A>kth41)
// ---------------------------------------------------------------------------
__global__ __launch_bounds__(256) void adj_kernel(const float* __restrict__ nv1,
                                                  const float* __restrict__ nv2,
                                                  float* __restrict__ keep) {
    int r = blockIdx.x, t = threadIdx.x;
    __shared__ float a[N_NODES];
    __shared__ float red[256];
    __shared__ int   redi[256];
    __shared__ int   taken[N_NODES];
    __shared__ float v1[10];
    __shared__ float kth;
    if (t < 10) v1[t] = nv1[r * 10 + t];
    __syncthreads();
    if (t < N_NODES) {
        float s = 0.f;
#pragma unroll
        for (int c = 0; c < 10; ++c) s += v1[c] * nv2[c * N_NODES + t];
        a[t] = fmaxf(s, 0.f);
        taken[t] = 0;
    }
    __syncthreads();
    red[t] = (t < N_NODES) ? a[t] : -3e38f;
    __syncthreads();
    for (int s = 128; s > 0; s >>= 1) {
        if (t < s) red[t] = fmaxf(red[t], red[t + s]);
        __syncthreads();
    }
    float mx = red[0];
    __syncthreads();
    float e = 0.f;
    if (t < N_NODES) e = __expf(a[t] - mx);
    red[t] = e;
    __syncthreads();
    for (int s = 128; s > 0; s >>= 1) {
        if (t < s) red[t] += red[t + s];
        __syncthreads();
    }
    float inv = 1.f / red[0];
    __syncthreads();
    if (t < N_NODES) a[t] = e * inv;
    __syncthreads();
    for (int round = 0; round <= MAX_NEIGH; ++round) {
        red[t]  = (t < N_NODES && !taken[t]) ? a[t] : -1.f;
        redi[t] = t;
        __syncthreads();
        for (int s = 128; s > 0; s >>= 1) {
            if (t < s && red[t + s] > red[t]) { red[t] = red[t + s]; redi[t] = redi[t + s]; }
            __syncthreads();
        }
        if (t == 0) {
            taken[redi[0]] = 1;
            if (round == MAX_NEIGH) kth = red[0];
        }
        __syncthreads();
    }
    if (t < N_NODES) {
        float av = a[t];
        keep[r * N_NODES + t] = (av > (1.f / 207.f) && av > kth) ? 1.f : 0.f;
    }
}

// mask bitwords: bit k of mw[q][w] = keep[uidx[q]/12][uidx[k]/12]
__global__ void maskbits_kernel(const float* __restrict__ keep, const int* __restrict__ uidx,
                                unsigned int* __restrict__ mw) {
    int q = blockIdx.x;
    int w = threadIdx.x;
    if (w >= NMW) return;
    const float* krow = keep + (uidx[q] / T_STEPS) * N_NODES;
    unsigned int word = 0;
    for (int j = 0; j < 32; ++j) {
        int k = w * 32 + j;
        if (k < N_UNMASK && krow[uidx[k] / T_STEPS] != 0.f) word |= (1u << j);
    }
    mw[q * NMW + w] = word;
}

__global__ void encin_kernel(const float* __restrict__ hist, const int* __restrict__ uidx,
                             const float* __restrict__ dim_w, const float* __restrict__ dim_b,
                             const float* __restrict__ pos,
                             const float* __restrict__ tod_w, const float* __restrict__ tod_b,
                             const float* __restrict__ dow_w, const float* __restrict__ dow_b,
                             float* __restrict__ h) {
    int idx = blockIdx.x * blockDim.x + threadIdx.x;
    if (idx >= BQ * N_UNMASK * DIM) return;
    int d = idx % DIM;
    int q = (idx / DIM) % N_UNMASK;
    int b = idx / (DIM * N_UNMASK);
    int u = uidx[q];
    int n = u / T_STEPS, t = u % T_STEPS;
    const float* hp = hist + ((size_t)(b * T_STEPS + t) * N_NODES + n) * 4;
    float h0 = hp[0], dw = hp[2], td = hp[3];
    float val = h0 * dim_w[d] + dim_b[d] + pos[u * DIM + d]
              + td * tod_w[d] + tod_b[d] + dw * dow_w[d] + dow_b[d];
    h[idx] = val * SQRT_DF;
}

__global__ void hmasked_kernel(const float* __restrict__ hist, const int* __restrict__ midx,
                               const float* __restrict__ mask_token, const float* __restrict__ pos,
                               const float* __restrict__ tod_w, const float* __restrict__ tod_b,
                               const float* __restrict__ dow_w, const float* __restrict__ dow_b,
                               float* __restrict__ full) {
    int idx = blockIdx.x * blockDim.x + threadIdx.x;
    if (idx >= BQ * N_MASK * DIM) return;
    int d = idx % DIM;
    int j = (idx / DIM) % N_MASK;
    int b = idx / (DIM * N_MASK);
    int m = midx[j];
    int n = m / T_STEPS, t = m % T_STEPS;
    const float* hp = hist + ((size_t)(b * T_STEPS + t) * N_NODES + n) * 4;
    float dw = hp[2], td = hp[3];
    float val = mask_token[d] + pos[m * DIM + d]
              + td * tod_w[d] + tod_b[d] + dw * dow_w[d] + dow_b[d];
    full[((size_t)(b * NT) + N_UNMASK + j) * DIM + d] = val * SQRT_DF;
}

__global__ void label_kernel(const float* __restrict__ hist, const int* __restrict__ midx,
                             float* __restrict__ out) {
    int idx = blockIdx.x * blockDim.x + threadIdx.x;
    if (idx >= BQ * N_MASK) return;
    int j = idx % N_MASK;
    int b = idx / N_MASK;
    int m = midx[j];
    int n = m / T_STEPS, t = m % T_STEPS;
    out[BQ * N_MASK + idx] = hist[((size_t)(b * T_STEPS + t) * N_NODES + n) * 4 + 0];
}

// ---------------------------------------------------------------------------
// Tiled GEMM: 64x64 tile, LDS-staged A and W, 16x16 threads x (4x4) outputs.
// WMODE 0: W is [K][N] row-major.  WMODE 1: W is [3][96][96] concat (QKV).
// rmode 1: residual rows gathered from full-layout masked region.
// omode 1: C rows scattered to full layout (row b*NT + q, q in [0,621)).
// LNA 1: LayerNorm staged A rows (K==96), params g1/b1; if wb && bn==0 write
//        normalized rows back to wb. LNA 2: two chained LNs.
// CMB 1: A rows are reconstructed in-LDS from attention partials
//        (Pm/Pl/Pacc, Sq2, NS2) — fused attn_combine. K must be 96.
// ---------------------------------------------------------------------------
#define ACCROW(accv, av)                                          \
    accv.x += av.x*w0.x + av.y*w1.x + av.z*w2.x + av.w*w3.x;      \
    accv.y += av.x*w0.y + av.y*w1.y + av.z*w2.y + av.w*w3.y;      \
    accv.z += av.x*w0.z + av.y*w1.z + av.z*w2.z + av.w*w3.z;      \
    accv.w += av.x*w0.w + av.y*w1.w + av.z*w2.w + av.w*w3.w;

template<int WMODE, int LNA, int CMB>
__global__ __launch_bounds__(256) void tgemm_kernel(const float* __restrict__ A,
                                                    const float* __restrict__ W,
                                                    const float* __restrict__ bias,
                                                    const float* __restrict__ res,
                                                    float* __restrict__ C,
                                                    int M, int N, int K, int gm,
                                                    int relu, float scale, int rmode,
                                                    int omode,
                                                    const float* __restrict__ g1,
                                                    const float* __restrict__ b1,
                                                    const float* __restrict__ g2,
                                                    const float* __restrict__ b2,
                                                    float* __restrict__ wb,
                                                    const float* __restrict__ Pm2,
                                                    const float* __restrict__ Pl2,
                                                    const float* __restrict__ Pacc2,
                                                    int Sq2, int NS2) {
    __shared__ float As[64][100];
    __shared__ float Ws[96][64];
    __shared__ float lred[64][4];
    __shared__ float lmv[64][2];
    int tid = threadIdx.x;
    int bm = blockIdx.x % gm;
    int bn = blockIdx.x / gm;
    int m0 = bm * 64, n0 = bn * 64;
    int tn4 = (tid & 15) * 4;
    int tm4 = (tid >> 4) * 4;
    float4 acc0 = {0,0,0,0}, acc1 = {0,0,0,0}, acc2 = {0,0,0,0}, acc3 = {0,0,0,0};

    for (int kc = 0; kc < K; kc += 96) {
        if (kc) __syncthreads();
        if (CMB) {
            // fused attention combine: 4 threads per row, one head each
            int r = tid >> 2, hh2 = tid & 3;
            int grow = m0 + r;
            float o[24];
#pragma unroll
            for (int d = 0; d < 24; ++d) o[d] = 0.f;
            float Lv = 1.f;
            if (grow < M) {
                int bb = grow / Sq2, q = grow - bb * Sq2;
                int bh = bb * NH + hh2;
                float Mx = -1e30f;
                for (int ns = 0; ns < NS2; ++ns)
                    Mx = fmaxf(Mx, Pm2[((size_t)(ns * NBH + bh)) * Sq2 + q]);
                Lv = 0.f;
                for (int ns = 0; ns < NS2; ++ns) {
                    size_t pq = ((size_t)(ns * NBH + bh)) * Sq2 + q;
                    float wgt = __expf(Pm2[pq] - Mx);
                    Lv += wgt * Pl2[pq];
                    const float* pa = Pacc2 + pq * 24;
#pragma unroll
                    for (int i = 0; i < 6; ++i) {
                        float4 f = *(const float4*)(pa + i * 4);
                        o[i*4+0] += wgt * f.x; o[i*4+1] += wgt * f.y;
                        o[i*4+2] += wgt * f.z; o[i*4+3] += wgt * f.w;
                    }
                }
            }
            float inv = 1.f / Lv;
#pragma unroll
            for (int i = 0; i < 6; ++i)
                *(float4*)&As[r][hh2 * 24 + i * 4] =
                    make_float4(o[i*4+0] * inv, o[i*4+1] * inv,
                                o[i*4+2] * inv, o[i*4+3] * inv);
        } else {
#pragma unroll
            for (int i = 0; i < 6; ++i) {
                int f = i * 256 + tid;
                int r = f / 24, c4 = (f % 24) * 4;
                float4 v = {0,0,0,0};
                if (m0 + r < M) v = *(const float4*)(A + (size_t)(m0 + r) * K + kc + c4);
                *(float4*)&As[r][c4] = v;
            }
        }
#pragma unroll
        for (int i = 0; i < 6; ++i) {
            int f = i * 256 + tid;
            int kr = f >> 4, n4 = (f & 15) * 4;
            int gn = n0 + n4;
            float4 v = {0,0,0,0};
            if (gn < N) {
                if (WMODE == 0) {
                    v = *(const float4*)(W + (size_t)(kc + kr) * N + gn);
                } else {
                    int gg = gn / 96, nc = gn - gg * 96;
                    v = *(const float4*)(W + (size_t)gg * 9216 + (kc + kr) * 96 + nc);
                }
            }
            *(float4*)&Ws[kr][n4] = v;
        }
        __syncthreads();

        if (LNA > 0 && kc == 0) {        // LNA implies K == 96 (single chunk)
#pragma unroll
            for (int pass = 0; pass < LNA; ++pass) {
                const float* lg = pass ? g2 : g1;
                const float* lb = pass ? b2 : b1;
                int row = tid >> 2, part = tid & 3;
                float s = 0.f;
                for (int c = part * 24; c < part * 24 + 24; ++c) s += As[row][c];
                lred[row][part] = s;
                __syncthreads();
                float mean = (lred[row][0] + lred[row][1] + lred[row][2] + lred[row][3]) * (1.f / 96.f);
                float s2 = 0.f;
                for (int c = part * 24; c < part * 24 + 24; ++c) {
                    float d = As[row][c] - mean; s2 += d * d;
                }
                __syncthreads();
                lred[row][part] = s2;
                __syncthreads();
                if (part == 0) {
                    float var = (lred[row][0] + lred[row][1] + lred[row][2] + lred[row][3]) * (1.f / 96.f);
                    lmv[row][0] = mean;
                    lmv[row][1] = rsqrtf(var + 1e-5f);
                }
                __syncthreads();
#pragma unroll
                for (int i = 0; i < 6; ++i) {
                    int f = i * 256 + tid;
                    int r = f / 24, c4 = (f % 24) * 4;
                    float mn = lmv[r][0], rsd = lmv[r][1];
                    float4 v = *(float4*)&As[r][c4];
                    v.x = (v.x - mn) * rsd * lg[c4 + 0] + lb[c4 + 0];
                    v.y = (v.y - mn) * rsd * lg[c4 + 1] + lb[c4 + 1];
                    v.z = (v.z - mn) * rsd * lg[c4 + 2] + lb[c4 + 2];
                    v.w = (v.w - mn) * rsd * lg[c4 + 3] + lb[c4 + 3];
                    *(float4*)&As[r][c4] = v;
                }
                __syncthreads();
            }
            if (wb && bn == 0) {
#pragma unroll
                for (int i = 0; i < 6; ++i) {
                    int f = i * 256 + tid;
                    int r = f / 24, c4 = (f % 24) * 4;
                    if (m0 + r < M)
                        *(float4*)(wb + (size_t)(m0 + r) * 96 + c4) = *(const float4*)&As[r][c4];
                }
            }
        }

#pragma unroll 4
        for (int k = 0; k < 96; k += 4) {
            float4 a0 = *(const float4*)&As[tm4 + 0][k];
            float4 a1 = *(const float4*)&As[tm4 + 1][k];
            float4 a2 = *(const float4*)&As[tm4 + 2][k];
            float4 a3 = *(const float4*)&As[tm4 + 3][k];
            float4 w0 = *(const float4*)&Ws[k + 0][tn4];
            float4 w1 = *(const float4*)&Ws[k + 1][tn4];
            float4 w2 = *(const float4*)&Ws[k + 2][tn4];
            float4 w3 = *(const float4*)&Ws[k + 3][tn4];
            ACCROW(acc0, a0)
            ACCROW(acc1, a1)
            ACCROW(acc2, a2)
            ACCROW(acc3, a3)
        }
    }

    int gn = n0 + tn4;
    if (gn >= N) return;
    float4 bv = *(const float4*)(bias + gn);
    float4 av[4] = {acc0, acc1, acc2, acc3};
#pragma unroll
    for (int i = 0; i < 4; ++i) {
        int grow = m0 + tm4 + i;
        if (grow >= M) break;
        float4 acc = av[i];
        acc.x += bv.x; acc.y += bv.y; acc.z += bv.z; acc.w += bv.w;
        if (res) {
            int rr = grow;
            if (rmode) { int bb = grow / N_MASK; rr = bb * NT + N_UNMASK + (grow - bb * N_MASK); }
            float4 rv = *(const float4*)(res + (size_t)rr * N + gn);
            acc.x += rv.x; acc.y += rv.y; acc.z += rv.z; acc.w += rv.w;
        }
        if (relu) {
            acc.x = fmaxf(acc.x, 0.f); acc.y = fmaxf(acc.y, 0.f);
            acc.z = fmaxf(acc.z, 0.f); acc.w = fmaxf(acc.w, 0.f);
        }
        acc.x *= scale; acc.y *= scale; acc.z *= scale; acc.w *= scale;
        int orow = grow;
        if (omode) { int bb = grow / N_UNMASK; orow = bb * NT + (grow - bb * N_UNMASK); }
        *(float4*)(C + (size_t)orow * N + gn) = acc;
    }
}

// ---------------------------------------------------------------------------
// Flash attention stage 1 (K-split, fp32 partials, ns-major storage).
// K-tiles interleaved across ns (c = ns, ns+NS, ...). swz=1: XCD-chunked
// decode (grid == 8 * 2 * nqt*NS): xcd=bid&7 serves bh in {xcd, xcd+8}.
// ---------------------------------------------------------------------------
template<int QPL>
__global__ __launch_bounds__(256) void fattn_kernel(const float* __restrict__ Qp,
                                                    const float* __restrict__ Kp,
                                                    const float* __restrict__ Vp,
                                                    float* __restrict__ Pm,
                                                    float* __restrict__ Pl,
                                                    float* __restrict__ Pacc,
                                                    const unsigned int* __restrict__ maskw,
                                                    int swz,
                                                    int S, int Sq, int qoff,
                                                    int nqt, int NS, int rs) {
    __shared__ float smem[12288];
    float* Ks = smem;
    float* Vs = smem + 6144;

    int t = threadIdx.x;
    int w = t >> 6, lane = t & 63;
    int bid = blockIdx.x;
    int ns, qt, hh, b;
    if (swz) {
        int xcd = bid & 7, slot = bid >> 3;
        int spb = nqt * NS;
        int bh = xcd + 8 * (slot / spb);
        int r = slot % spb;
        qt = r / NS; ns = r % NS;
        b = bh >> 2; hh = bh & 3;
    } else {
        ns = bid % NS; int r1 = bid / NS;
        qt = r1 % nqt; r1 /= nqt;
        hh = r1 % NH; b = r1 / NH;
    }

    float qr[QPL][HD];
    bool qvalid[QPL];
#pragma unroll
    for (int h = 0; h < QPL; ++h) {
        int qidx = qt * (64 * QPL) + h * 64 + lane;
        qvalid[h] = qidx < Sq;
        if (qvalid[h]) {
            const float* qp = Qp + ((size_t)(b * S + qoff + qidx)) * rs + hh * HD;
#pragma unroll
            for (int i = 0; i < 6; ++i) {
                float4 v = *(const float4*)(qp + i * 4);
                qr[h][i*4+0] = v.x; qr[h][i*4+1] = v.y;
                qr[h][i*4+2] = v.z; qr[h][i*4+3] = v.w;
            }
        } else {
#pragma unroll
            for (int d = 0; d < HD; ++d) qr[h][d] = 0.f;
        }
    }

    float m[QPL], l[QPL];
    float acc[QPL][HD];
#pragma unroll
    for (int h = 0; h < QPL; ++h) {
        m[h] = -1e30f; l[h] = 0.f;
#pragma unroll
        for (int d = 0; d < HD; ++d) acc[h][d] = 0.f;
    }

    int ntile = (S + KT - 1) / KT;
    for (int c = ns; c < ntile; c += NS) {
        __syncthreads();
        int base_k = c * KT;
#pragma unroll
        for (int i = 0; i < 6; ++i) {
            int fi = i * 256 + t;
            int row = fi / 6, cc = fi - row * 6;
            int gk = base_k + row;
            float4 kv = {0,0,0,0};
            float4 vv = {0,0,0,0};
            if (gk < S) {
                size_t roff = ((size_t)(b * S + gk)) * rs + hh * HD + cc * 4;
                kv = *(const float4*)(Kp + roff);
                vv = *(const float4*)(Vp + roff);
            }
            *(float4*)(Ks + row * HD + cc * 4) = kv;
            *(float4*)(Vs + row * HD + cc * 4) = vv;
        }
        __syncthreads();

        unsigned int mw0 = ~0u, mw1 = ~0u;
        if (QPL == 1 && maskw) {
            int qidx = qt * 64 + lane;
            if (qidx < Sq) {
                int wi = c * 8 + w * 2;
                mw0 = (wi     < NMW) ? maskw[qidx * NMW + wi]     : 0u;
                mw1 = (wi + 1 < NMW) ? maskw[qidx * NMW + wi + 1] : 0u;
            }
        }

        for (int g = 0; g < 16; ++g) {
            float sgrp[QPL][4];
            float pv[QPL][4];
#pragma unroll
            for (int j = 0; j < 4; ++j) {
                int j2 = g * 4 + j;
                int kk = (w << 6) + j2;
                int gk = base_k + kk;
                const float4* kr = (const float4*)(Ks + kk * HD);
                float d0[QPL];
#pragma unroll
                for (int h = 0; h < QPL; ++h) d0[h] = 0.f;
#pragma unroll
                for (int i = 0; i < 6; ++i) {
                    float4 kv = kr[i];
#pragma unroll
                    for (int h = 0; h < QPL; ++h) {
                        d0[h] += qr[h][i*4+0]*kv.x + qr[h][i*4+1]*kv.y
                               + qr[h][i*4+2]*kv.z + qr[h][i*4+3]*kv.w;
                    }
                }
#pragma unroll
                for (int h = 0; h < QPL; ++h) {
                    float s = d0[h] * ATTN_SCALE;
                    if (QPL == 1 && maskw) {
                        unsigned int wsel = (j2 & 32) ? mw1 : mw0;
                        if (!((wsel >> (j2 & 31)) & 1u)) s = -1e30f;
                    }
                    if (gk >= S) s = -INFINITY;
                    sgrp[h][j] = s;
                }
            }
#pragma unroll
            for (int h = 0; h < QPL; ++h) {
                float gmx = fmaxf(fmaxf(sgrp[h][0], sgrp[h][1]),
                                  fmaxf(sgrp[h][2], sgrp[h][3]));
                if (gmx > m[h]) {
                    float f = __expf(m[h] - gmx);
                    l[h] *= f;
#pragma unroll
                    for (int d = 0; d < HD; ++d) acc[h][d] *= f;
                    m[h] = gmx;
                }
#pragma unroll
                for (int j = 0; j < 4; ++j) {
                    float p = __expf(sgrp[h][j] - m[h]);
                    pv[h][j] = p;
                    l[h] += p;
                }
            }
#pragma unroll
            for (int j = 0; j < 4; ++j) {
                int kk = (w << 6) + g * 4 + j;
                const float4* vr = (const float4*)(Vs + kk * HD);
#pragma unroll
                for (int i = 0; i < 6; ++i) {
                    float4 vv = vr[i];
#pragma unroll
                    for (int h = 0; h < QPL; ++h) {
                        acc[h][i*4+0] += pv[h][j]*vv.x;
                        acc[h][i*4+1] += pv[h][j]*vv.y;
                        acc[h][i*4+2] += pv[h][j]*vv.z;
                        acc[h][i*4+3] += pv[h][j]*vv.w;
                    }
                }
            }
        }
    }

#pragma unroll
    for (int h = 0; h < QPL; ++h) {
        __syncthreads();
        float* my = smem + (size_t)(w * 64 + lane) * 27;
        my[0] = m[h]; my[1] = l[h];
#pragma unroll
        for (int d = 0; d < HD; ++d) my[2 + d] = acc[h][d];
        __syncthreads();
        if (t < 64) {
            int qidx = qt * (64 * QPL) + h * 64 + t;
            if (qidx < Sq) {
                float M2 = -INFINITY;
#pragma unroll
                for (int w2 = 0; w2 < 4; ++w2)
                    M2 = fmaxf(M2, smem[(size_t)(w2 * 64 + t) * 27]);
                float L = 0.f;
                float o[HD];
#pragma unroll
                for (int d = 0; d < HD; ++d) o[d] = 0.f;
#pragma unroll
                for (int w2 = 0; w2 < 4; ++w2) {
                    const float* pp = smem + (size_t)(w2 * 64 + t) * 27;
                    float f = __expf(pp[0] - M2);
                    L += pp[1] * f;
#pragma unroll
                    for (int d = 0; d < HD; ++d) o[d] += pp[2 + d] * f;
                }
                int bh = b * NH + hh;
                size_t pq = ((size_t)(ns * NBH + bh)) * Sq + qidx;
                Pm[pq] = M2;
                Pl[pq] = L;
                float* pa = Pacc + pq * 24;
#pragma unroll
                for (int i = 0; i < 6; ++i)
                    *(float4*)(pa + i * 4) = make_float4(o[i*4+0], o[i*4+1],
                                                         o[i*4+2], o[i*4+3]);
            }
        }
    }
}

// fused LN -> LN -> out-projection for the masked tail rows
__global__ __launch_bounds__(256) void tail_kernel(const float* __restrict__ X,
                                                   const float* __restrict__ g1,
                                                   const float* __restrict__ b1,
                                                   const float* __restrict__ g2,
                                                   const float* __restrict__ b2,
                                                   const float* __restrict__ ow,
                                                   const float* __restrict__ ob,
                                                   float* __restrict__ out, int Mtail) {
    int row = blockIdx.x * 4 + (threadIdx.x >> 6);
    if (row >= Mtail) return;
    int lane = threadIdx.x & 63;
    bool lo = lane < 32;
    const float* x = X + (size_t)row * DIM;
    float x0 = x[lane];
    float x1 = lo ? x[64 + lane] : 0.f;
    float s = x0 + x1;
#pragma unroll
    for (int o = 32; o; o >>= 1) s += __shfl_xor(s, o);
    float mean = s * (1.f / DIM);
    float d0 = x0 - mean;
    float d1 = lo ? (x1 - mean) : 0.f;
    float v = d0 * d0 + d1 * d1;
#pragma unroll
    for (int o = 32; o; o >>= 1) v += __shfl_xor(v, o);
    float rs = rsqrtf(v * (1.f / DIM) + 1e-5f);
    float y0 = d0 * rs * g1[lane] + b1[lane];
    float y1 = lo ? (d1 * rs * g1[64 + lane] + b1[64 + lane]) : 0.f;
    s = y0 + y1;
#pragma unroll
    for (int o = 32; o; o >>= 1) s += __shfl_xor(s, o);
    mean = s * (1.f / DIM);
    d0 = y0 - mean;
    d1 = lo ? (y1 - mean) : 0.f;
    v = d0 * d0 + d1 * d1;
#pragma unroll
    for (int o = 32; o; o >>= 1) v += __shfl_xor(v, o);
    rs = rsqrtf(v * (1.f / DIM) + 1e-5f);
    float z0 = d0 * rs * g2[lane] + b2[lane];
    float z1 = lo ? (d1 * rs * g2[64 + lane] + b2[64 + lane]) : 0.f;
    float a = z0 * ow[lane] + (lo ? z1 * ow[64 + lane] : 0.f);
#pragma unroll
    for (int o = 32; o; o >>= 1) a += __shfl_xor(a, o);
    if (lane == 0) out[row] = a + ob[0];
}

extern "C" void kernel_launch(void* const* d_in, const int* in_sizes, int n_in,
                              void* d_out, int out_size, void* d_ws, size_t ws_size,
                              hipStream_t stream) {
    const float* hist   = (const float*)d_in[0];
    const int*   uidx   = (const int*)d_in[1];
    const int*   midx   = (const int*)d_in[2];
    const float* nv1    = (const float*)d_in[3];
    const float* nv2    = (const float*)d_in[4];
    const float* dim_w  = (const float*)d_in[5];
    const float* dim_b  = (const float*)d_in[6];
    const float* pos    = (const float*)d_in[7];
    const float* tod_w  = (const float*)d_in[8];
    const float* tod_b  = (const float*)d_in[9];
    const float* dow_w  = (const float*)d_in[10];
    const float* dow_b  = (const float*)d_in[11];
    const float* mtok   = (const float*)d_in[12];
    const float* eaw    = (const float*)d_in[13];
    const float* eab    = (const float*)d_in[14];
    const float* ew1    = (const float*)d_in[15];
    const float* eb1    = (const float*)d_in[16];
    const float* ew2    = (const float*)d_in[17];
    const float* eb2    = (const float*)d_in[18];
    const float* eln    = (const float*)d_in[19];
    const float* eng    = (const float*)d_in[20];
    const float* enb    = (const float*)d_in[21];
    const float* e2dw   = (const float*)d_in[22];
    const float* e2db   = (const float*)d_in[23];
    const float* daw    = (const float*)d_in[24];
    const float* dab    = (const float*)d_in[25];
    const float* dw1    = (const float*)d_in[26];
    const float* db1    = (const float*)d_in[27];
    const float* dw2    = (const float*)d_in[28];
    const float* db2    = (const float*)d_in[29];
    const float* dln    = (const float*)d_in[30];
    const float* dng    = (const float*)d_in[31];
    const float* dnb    = (const float*)d_in[32];
    const float* ow     = (const float*)d_in[33];
    const float* ob     = (const float*)d_in[34];

    float* ws = (float*)d_ws;
    float*        keep  = ws;                               // 0..43008
    unsigned int* maskw = (unsigned int*)(ws + 44032);      // ..56576
    float* eh = ws + 56576;            // [2484][96]  -> 295040
    float* e1 = ws + 295040;           // [2484][384] -> 1248896
    float* et = ws + 1487360;          // [2484][96]  -> 1725824
    float* fh = ws + 1725824;          // [9936][96]  -> 2679680
    float* qf = ws + 2679680;          // [9936][288] -> 5541248 (also dec FF-mid [7452][384])
    float* dh = ws + 5541248;          // [7452][96]  -> 6256640
    float* dt = ws + 6256640;          // [7452][96]  -> 6972032
    // encoder attn partials overlay dead dh (NSE=3, Sq=621):
    float* PaccE = ws + 5541248;       // 715392 -> 6256640
    float* PmE   = ws + 6256640;       // 29808 -> 6286448
    float* PlE   = ws + 6286448;       // 29808 -> 6316256
    // decoder attn partials overlay dead encoder temps (NSD=2, Sq=1863):
    float* PaccD = ws + 56576;         // 2*16*1863*24 = 1430784 -> 1487360
    float* PmD   = ws + 1487360;       // 59616 -> 1546976
    float* PlD   = ws + 1546976;       // 59616 -> 1606592 (< 1725824 = fh)
    // decoder post-attention temps:
    //   O-proj(CMB from partials, +fh res) -> dt ; FF1(LNA dt, wb=dZ) -> qf ;
    //   FF2(qf, +dZ res) -> dh ; tail(dh)
    float* dZ = ws + 771968;           // [7452][96] -> 1487360 (partials dead by FF1)

    float* outp = (float*)d_out;
    const int ME = BQ * N_UNMASK;   // 2484
    const int MD = BQ * NT;         // 9936
    const int MT = BQ * N_MASK;     // 7452
    const int gmE = cdiv(ME, 64);   // 39
    const int gmD = cdiv(MD, 64);   // 156
    const int gmT = cdiv(MT, 64);   // 117
    const int NSE = 3, NSD = 2;
    const int nqtE = 10;            // ceil(621/64),   QPL=1 ; grid 480 = 8*2*30
    const int nqtD = 15;            // ceil(1863/128), QPL=2 ; grid 480 = 8*2*30

    adj_kernel<<<N_NODES, 256, 0, stream>>>(nv1, nv2, keep);
    maskbits_kernel<<<N_UNMASK, 32, 0, stream>>>(keep, uidx, maskw);
    encin_kernel<<<cdiv(ME * DIM, 256), 256, 0, stream>>>(
        hist, uidx, dim_w, dim_b, pos, tod_w, tod_b, dow_w, dow_b, eh);
    label_kernel<<<cdiv(MT, 256), 256, 0, stream>>>(hist, midx, outp);

    // ---------------- encoder: 4 layers, S=621 ----------------
    for (int l = 0; l < 4; ++l) {
        const float* aw = eaw + (size_t)l * 4 * DIM * DIM;
        const float* ab = eab + (size_t)l * 4 * DIM;
        if (l == 0) {
            tgemm_kernel<1,0,0><<<gmE * 5, 256, 0, stream>>>(
                eh, aw, ab, nullptr, e1, ME, 288, 96, gmE, 0, 1.f, 0, 0,
                nullptr, nullptr, nullptr, nullptr, nullptr,
                nullptr, nullptr, nullptr, 0, 0);
        } else {
            // A = et (prev FF2 out, pre-LN2); LN2(l-1) fused; write back to eh
            tgemm_kernel<1,1,0><<<gmE * 5, 256, 0, stream>>>(
                et, aw, ab, nullptr, e1, ME, 288, 96, gmE, 0, 1.f, 0, 0,
                eln + (size_t)((l - 1) * 4 + 2) * DIM,
                eln + (size_t)((l - 1) * 4 + 3) * DIM,
                nullptr, nullptr, eh,
                nullptr, nullptr, nullptr, 0, 0);
        }
        fattn_kernel<1><<<NBH * nqtE * NSE, 256, 0, stream>>>(
            e1, e1 + 96, e1 + 192, PmE, PlE, PaccE, maskw, 1,
            N_UNMASK, N_UNMASK, 0, nqtE, NSE, 288);
        // O-proj with fused combine (A from partials) + residual eh -> et
        tgemm_kernel<0,0,1><<<gmE * 2, 256, 0, stream>>>(
            nullptr, aw + 3 * DIM * DIM, ab + 3 * DIM, eh, et, ME, 96, 96, gmE,
            0, 1.f, 0, 0,
            nullptr, nullptr, nullptr, nullptr, nullptr,
            PmE, PlE, PaccE, N_UNMASK, NSE);
        // FF1 with fused LN1 (A = et pre-LN1); write LN1 rows back to eh
        tgemm_kernel<0,1,0><<<gmE * 6, 256, 0, stream>>>(
            et, ew1 + (size_t)l * DIM * FFD, eb1 + (size_t)l * FFD, nullptr, e1,
            ME, FFD, 96, gmE, 1, 1.f, 0, 0,
            eln + (size_t)(l * 4 + 0) * DIM, eln + (size_t)(l * 4 + 1) * DIM,
            nullptr, nullptr, eh,
            nullptr, nullptr, nullptr, 0, 0);
        tgemm_kernel<0,0,0><<<gmE * 2, 256, 0, stream>>>(
            e1, ew2 + (size_t)l * FFD * DIM, eb2 + (size_t)l * DIM, eh, et,
            ME, 96, FFD, gmE, 0, 1.f, 0, 0,
            nullptr, nullptr, nullptr, nullptr, nullptr,
            nullptr, nullptr, nullptr, 0, 0);
        // (LN2 folded into next consumer's A-stage)
    }
    // e2d with fused LN2(l3) + final norm, *sqrt(D), scattered into fh (omode=1)
    tgemm_kernel<0,2,0><<<gmE * 2, 256, 0, stream>>>(
        et, e2dw, e2db, nullptr, fh, ME, 96, 96, gmE, 0, SQRT_DF, 0, 1,
        eln + (size_t)(3 * 4 + 2) * DIM, eln + (size_t)(3 * 4 + 3) * DIM,
        eng, enb, nullptr,
        nullptr, nullptr, nullptr, 0, 0);
    hmasked_kernel<<<cdiv(MT * DIM, 256), 256, 0, stream>>>(
        hist, midx, mtok, pos, tod_w, tod_b, dow_w, dow_b, fh);

    // ---------------- decoder: 1 layer; only masked q-rows survive ----------
    tgemm_kernel<1,0,0><<<gmD * 5, 256, 0, stream>>>(
        fh, daw, dab, nullptr, qf, MD, 288, 96, gmD, 0, 1.f, 0, 0,
        nullptr, nullptr, nullptr, nullptr, nullptr,
        nullptr, nullptr, nullptr, 0, 0);
    // QPL=2, NS=2, swizzled -> 480 blocks (the proven optimum)
    fattn_kernel<2><<<NBH * nqtD * NSD, 256, 0, stream>>>(
        qf, qf + 96, qf + 192, PmD, PlD, PaccD, nullptr, 1,
        NT, N_MASK, N_UNMASK, nqtD, NSD, 288);
    // O-proj with fused combine + residual gathered from fh (rmode=1) -> dt
    tgemm_kernel<0,0,1><<<gmT * 2, 256, 0, stream>>>(
        nullptr, daw + 3 * DIM * DIM, dab + 3 * DIM, fh, dt, MT, 96, 96, gmT,
        0, 1.f, 1, 0,
        nullptr, nullptr, nullptr, nullptr, nullptr,
        PmD, PlD, PaccD, N_MASK, NSD);
    // FF1 with fused LN1 (A = dt pre-LN1); write LN1 rows back to dZ
    tgemm_kernel<0,1,0><<<gmT * 6, 256, 0, stream>>>(
        dt, dw1, db1, nullptr, qf, MT, FFD, 96, gmT, 1, 1.f, 0, 0,
        dln + 0 * DIM, dln + 1 * DIM, nullptr, nullptr, dZ,
        nullptr, nullptr, nullptr, 0, 0);
    tgemm_kernel<0,0,0><<<gmT * 2, 256, 0, stream>>>(
        qf, dw2, db2, dZ, dh, MT, 96, FFD, gmT, 0, 1.f, 0, 0,
        nullptr, nullptr, nullptr, nullptr, nullptr,
        nullptr, nullptr, nullptr, 0, 0);
    tail_kernel<<<cdiv(MT, 4), 256, 0, stream>>>(
        dh, dln + 2 * DIM, dln + 3 * DIM, dng, dnb, ow, ob, outp, MT);
}